// Round 1
// baseline (3430.240 us; speedup 1.0000x reference)
//
#include <hip/hip_runtime.h>

// ---------------------------------------------------------------------------
// gmm_hyper_y2: 3-branch conv hypernetwork on MI355X (gfx950).
// Strategy: bf16 MFMA implicit-GEMM convs, NHWC bf16 activations,
// weights pre-swizzled to MFMA A-fragment order (loaded global->reg),
// activation halo tiles staged in LDS with chunk XOR-swizzle.
// ---------------------------------------------------------------------------

typedef __attribute__((ext_vector_type(8))) short   short8;
typedef __attribute__((ext_vector_type(4))) float   f32x4;
typedef __attribute__((ext_vector_type(4))) unsigned short u16x4;

#define DEV __device__ __forceinline__

DEV unsigned short f2bf(float f) {           // RTNE f32 -> bf16
  union { float f; unsigned u; } v; v.f = f;
  unsigned u = v.u;
  u += 0x7fffu + ((u >> 16) & 1u);
  return (unsigned short)(u >> 16);
}

// ---------------- weight prep: OIHW f32 -> frag-order bf16 -----------------
// dst layout: [tap(25)][kt(CIN/32)][mt(COUTP/16)][lane(64)][j(8)]
// element = w[co = mt*16 + (l&15)][ci = kt*32 + (l>>4)*8 + j][ky][kx]
template<int CIN, int COUT, int COUTP>
__global__ void prep_w(const float* __restrict__ w, unsigned short* __restrict__ dst) {
  const int KT = CIN / 32, MT = COUTP / 16;
  const int total = 25 * KT * MT * 512;
  for (int idx = blockIdx.x * blockDim.x + threadIdx.x; idx < total;
       idx += gridDim.x * blockDim.x) {
    int j   = idx & 7;
    int l   = (idx >> 3) & 63;
    int blk = idx >> 9;
    int mt  = blk % MT;
    int rst = blk / MT;
    int kt  = rst % KT;
    int tap = rst / KT;
    int ky = tap / 5, kx = tap % 5;
    int co = mt * 16 + (l & 15);
    int ci = kt * 32 + (l >> 4) * 8 + j;
    float val = (co < COUT) ? w[((co * CIN + ci) * 5 + ky) * 5 + kx] : 0.0f;
    dst[idx] = f2bf(val);
  }
}

// ------------- upsample z2 x4 bilinear + concat y1 -> NHWC bf16 ------------
// cat layout: [b][Y][X][c(320)]; c<128 = upsample(z2), c>=128 = y1
__global__ void upsample_cat_k(const float* __restrict__ z2,
                               const float* __restrict__ y1,
                               unsigned short* __restrict__ cat) {
  int tid = blockIdx.x * blockDim.x + threadIdx.x;
  int p = tid % 9216;
  int rest = tid / 9216;
  int chunk = rest % 40;
  int b = rest / 40;
  if (b >= 8) return;
  int Y = p / 96, X = p % 96;
  short8 vec;
  if (chunk < 16) {
    const float s = 23.0f / 95.0f;        // linspace(0,23,96) step
    float ys = Y * s, xs = X * s;
    float fy = floorf(ys), fx = floorf(xs);
    int y0 = (int)fy, x0 = (int)fx;
    int y1i = min(y0 + 1, 23), x1i = min(x0 + 1, 23);
    float wy = ys - fy, wx = xs - fx;
    int c0 = chunk * 8;
    const float* zb = z2 + ((size_t)b * 128 + c0) * 576;
#pragma unroll
    for (int i = 0; i < 8; ++i) {
      const float* zc = zb + (size_t)i * 576;
      float g00 = zc[y0 * 24 + x0],  g01 = zc[y0 * 24 + x1i];
      float g10 = zc[y1i * 24 + x0], g11 = zc[y1i * 24 + x1i];
      float top = g00 + (g01 - g00) * wx;
      float bot = g10 + (g11 - g10) * wx;
      vec[i] = (short)f2bf(top + (bot - top) * wy);
    }
  } else {
    int c0 = (chunk - 16) * 8;
    const float* yb = y1 + ((size_t)b * 192 + c0) * 9216 + p;
#pragma unroll
    for (int i = 0; i < 8; ++i) vec[i] = (short)f2bf(yb[(size_t)i * 9216]);
  }
  int cbase = (chunk < 16) ? chunk * 8 : 128 + (chunk - 16) * 8;
  *reinterpret_cast<short8*>(cat + ((size_t)(b * 9216 + p)) * 320 + cbase) = vec;
}

// --------------------------- 5x5 conv, pad 2 --------------------------------
// Block: 256 thr = 4 waves (wm = co-half, wn = row). Tile: 128 co x (2 rows x 96 px).
// Per wave: 4 co-frags x 6 px-frags of 16x16x32 bf16 MFMA.
// OUTMODE: 0 = bf16 NHWC, 1 = f32 NCHW (final), 2 = global-max partials.
// ACT: 0 none, 1 relu, 2 lrelu(0.01).
template<int CIN, int COUT, int COUTP, int ACT, int OUTMODE>
__global__ __launch_bounds__(256)
void conv5_k(const unsigned short* __restrict__ act_in,
             const unsigned short* __restrict__ wfrag,
             const float* __restrict__ bias,
             float* __restrict__ out_f32,
             unsigned short* __restrict__ out_bf16,
             float* __restrict__ part) {
  const int KT = CIN / 32, MT = COUTP / 16;
  __shared__ alignas(16) char lds[600 * 64];   // 6 rows x 100 cols x 32ci bf16
  const int tid = threadIdx.x;
  const int l = tid & 63;
  const int wid = tid >> 6;
  const int wm = wid & 1, wn = wid >> 1;
  const int rowtile = blockIdx.x;              // 0..47
  const int coblk = blockIdx.y * 128;
  const int b = blockIdx.z;
  const int y0 = rowtile * 2;
  const int lj = l >> 4, lx = l & 15;

  f32x4 acc[4][6];
#pragma unroll
  for (int m = 0; m < 4; ++m) {
#pragma unroll
    for (int n = 0; n < 6; ++n) acc[m][n] = f32x4{0.f, 0.f, 0.f, 0.f};
  }

  for (int kt = 0; kt < KT; ++kt) {
    __syncthreads();                           // protect LDS from prev-iter reads
    // ---- stage 6x100x32ci halo tile, chunk-XOR-swizzled, zero-padded ----
    for (int t = tid; t < 2400; t += 256) {
      int p = t >> 2, q = t & 3;
      int r = p / 100;
      int c = p - r * 100;
      int yy = y0 + r - 2, xx = c - 2;
      int chunk = q ^ ((c >> 1) & 3);
      short8 v = {0, 0, 0, 0, 0, 0, 0, 0};
      if ((unsigned)yy < 96u && (unsigned)xx < 96u)
        v = *reinterpret_cast<const short8*>(
            act_in + (size_t)((b * 96 + yy) * 96 + xx) * CIN + kt * 32 + chunk * 8);
      *reinterpret_cast<short8*>(&lds[t * 16]) = v;
    }
    __syncthreads();

    const unsigned short* wb =
        wfrag + ((size_t)kt * MT + (coblk >> 4) + wm * 4) * 512 + l * 8;
    for (int ky = 0; ky < 5; ++ky) {
      const int r = wn + ky;
#pragma unroll
      for (int kx = 0; kx < 5; ++kx) {
        const int tap = ky * 5 + kx;
        short8 aW[4];
#pragma unroll
        for (int m = 0; m < 4; ++m)
          aW[m] = *reinterpret_cast<const short8*>(wb + ((size_t)tap * KT * MT + m) * 512);
        short8 bA[6];
#pragma unroll
        for (int n = 0; n < 6; ++n) {
          int c = kx + n * 16 + lx;
          int off = ((r * 100 + c) << 6) + ((lj ^ ((c >> 1) & 3)) << 4);
          bA[n] = *reinterpret_cast<const short8*>(&lds[off]);
        }
#pragma unroll
        for (int m = 0; m < 4; ++m) {
#pragma unroll
          for (int n = 0; n < 6; ++n)
            acc[m][n] = __builtin_amdgcn_mfma_f32_16x16x32_bf16(aW[m], bA[n], acc[m][n], 0, 0, 0);
        }
      }
    }
  }

  const int yout = y0 + wn;
  if (OUTMODE == 0) {
#pragma unroll
    for (int m = 0; m < 4; ++m) {
      int co0 = coblk + wm * 64 + m * 16 + lj * 4;
      f32x4 bv = *reinterpret_cast<const f32x4*>(bias + co0);
#pragma unroll
      for (int n = 0; n < 6; ++n) {
        int x = n * 16 + lx;
        u16x4 pk;
#pragma unroll
        for (int j = 0; j < 4; ++j) {
          float v = acc[m][n][j] + bv[j];
          if (ACT == 1) v = fmaxf(v, 0.f);
          if (ACT == 2) v = (v >= 0.f) ? v : 0.01f * v;
          pk[j] = f2bf(v);
        }
        *reinterpret_cast<u16x4*>(
            out_bf16 + (size_t)((b * 96 + yout) * 96 + x) * COUT + co0) = pk;
      }
    }
  } else if (OUTMODE == 1) {
#pragma unroll
    for (int m = 0; m < 4; ++m) {
      int co0 = coblk + wm * 64 + m * 16 + lj * 4;
      if (co0 < COUT) {
        f32x4 bv = *reinterpret_cast<const f32x4*>(bias + co0);
#pragma unroll
        for (int n = 0; n < 6; ++n) {
          int x = n * 16 + lx;
#pragma unroll
          for (int j = 0; j < 4; ++j) {
            float v = acc[m][n][j] + bv[j];
            if (ACT == 1) v = fmaxf(v, 0.f);
            if (ACT == 2) v = (v >= 0.f) ? v : 0.01f * v;
            out_f32[((size_t)(b * COUT + co0 + j) * 96 + yout) * 96 + x] = v;
          }
        }
      }
    }
  } else {  // OUTMODE == 2: conv+bias -> max over this block's 96 px per row
#pragma unroll
    for (int m = 0; m < 4; ++m) {
      int co0 = coblk + wm * 64 + m * 16 + lj * 4;
      f32x4 bv = f32x4{0.f, 0.f, 0.f, 0.f};
      if (co0 < COUT) bv = *reinterpret_cast<const f32x4*>(bias + co0);
#pragma unroll
      for (int j = 0; j < 4; ++j) {
        float mx = -3.0e38f;
#pragma unroll
        for (int n = 0; n < 6; ++n) mx = fmaxf(mx, acc[m][n][j] + bv[j]);
#pragma unroll
        for (int s = 1; s < 16; s <<= 1) mx = fmaxf(mx, __shfl_xor(mx, s, 64));
        if (lx == 0 && co0 + j < COUT)
          part[(size_t)(b * COUT + co0 + j) * 96 + rowtile * 2 + wn] = mx;
      }
    }
  }
}

// --------------------- tail: reduce / 1x1 conv / softmax -------------------
__global__ void reduce_max_k(const float* __restrict__ part, float* __restrict__ pooled) {
  int i = blockIdx.x * blockDim.x + threadIdx.x;
  if (i >= 8 * 576) return;
  const float* p = part + (size_t)i * 96;
  float mx = p[0];
  for (int t = 1; t < 96; ++t) mx = fmaxf(mx, p[t]);
  pooled[i] = mx;
}

__global__ void tail_k(const float* __restrict__ pooled,
                       const float* __restrict__ ww3, const float* __restrict__ bw3,
                       float* __restrict__ outw) {
  __shared__ float g[576];
  __shared__ float h2[576];
  int b = blockIdx.x, tid = threadIdx.x;
  for (int i = tid; i < 576; i += 256) {
    float v = pooled[b * 576 + i];
    g[i] = (v >= 0.f) ? v : 0.01f * v;      // lrelu after maxpool
  }
  __syncthreads();
  for (int o = tid; o < 576; o += 256) {
    float s = bw3[o];
    const float* wr = ww3 + (size_t)o * 576;
    for (int i = 0; i < 576; ++i) s += wr[i] * g[i];
    h2[o] = s;
  }
  __syncthreads();
  for (int m = tid; m < 192; m += 256) {
    float a0 = h2[m], a1 = h2[192 + m], a2 = h2[384 + m];
    float mx = fmaxf(a0, fmaxf(a1, a2));
    float e0 = expf(a0 - mx), e1 = expf(a1 - mx), e2 = expf(a2 - mx);
    float inv = 1.f / (e0 + e1 + e2);
    outw[b * 576 + m]       = e0 * inv;
    outw[b * 576 + 192 + m] = e1 * inv;
    outw[b * 576 + 384 + m] = e2 * inv;
  }
}

// ---------------------------------------------------------------------------
extern "C" void kernel_launch(void* const* d_in, const int* in_sizes, int n_in,
                              void* d_out, int out_size, void* d_ws, size_t ws_size,
                              hipStream_t stream) {
  const float* z2  = (const float*)d_in[0];
  const float* y1  = (const float*)d_in[1];
  const float* ws1 = (const float*)d_in[2];  const float* bs1 = (const float*)d_in[3];
  const float* ws2 = (const float*)d_in[4];  const float* bs2 = (const float*)d_in[5];
  const float* ws3 = (const float*)d_in[6];  const float* bs3 = (const float*)d_in[7];
  const float* wm1 = (const float*)d_in[8];  const float* bm1 = (const float*)d_in[9];
  const float* wm2 = (const float*)d_in[10]; const float* bm2 = (const float*)d_in[11];
  const float* wm3 = (const float*)d_in[12]; const float* bm3 = (const float*)d_in[13];
  const float* ww1 = (const float*)d_in[14]; const float* bw1 = (const float*)d_in[15];
  const float* ww2 = (const float*)d_in[16]; const float* bw2 = (const float*)d_in[17];
  const float* ww3 = (const float*)d_in[18]; const float* bw3 = (const float*)d_in[19];

  char* ws = (char*)d_ws;
  size_t off = 0;
  auto alloc = [&](size_t bytes) -> char* {
    char* p = ws + off;
    off += (bytes + 255) & ~(size_t)255;
    return p;
  };
  unsigned short* cat = (unsigned short*)alloc(8ull * 9216 * 320 * 2);
  unsigned short* t1  = (unsigned short*)alloc(8ull * 9216 * 128 * 2);
  unsigned short* t2  = (unsigned short*)alloc(8ull * 9216 * 128 * 2);
  const size_t szA = 25ull * 10 * 8 * 512;   // 320 -> 128
  const size_t szB = 25ull * 4 * 8 * 512;    // 128 -> 128
  const size_t szC = 25ull * 4 * 40 * 512;   // 128 -> 640 (576 padded)
  unsigned short* Ws1 = (unsigned short*)alloc(szA * 2);
  unsigned short* Ws2 = (unsigned short*)alloc(szB * 2);
  unsigned short* Ws3 = (unsigned short*)alloc(szC * 2);
  unsigned short* Wm1 = (unsigned short*)alloc(szA * 2);
  unsigned short* Wm2 = (unsigned short*)alloc(szB * 2);
  unsigned short* Wm3 = (unsigned short*)alloc(szC * 2);
  unsigned short* Ww1 = (unsigned short*)alloc(szA * 2);
  unsigned short* Ww2 = (unsigned short*)alloc(szC * 2);
  float* part   = (float*)alloc(8ull * 576 * 96 * 4);
  float* pooled = (float*)alloc(8ull * 576 * 4);

  float* out_sigma = (float*)d_out;
  float* out_means = out_sigma + 8ull * 576 * 9216;
  float* out_w     = out_means + 8ull * 576 * 9216;

  // weight prep
  prep_w<320, 128, 128><<<512, 256, 0, stream>>>(ws1, Ws1);
  prep_w<128, 128, 128><<<512, 256, 0, stream>>>(ws2, Ws2);
  prep_w<128, 576, 640><<<512, 256, 0, stream>>>(ws3, Ws3);
  prep_w<320, 128, 128><<<512, 256, 0, stream>>>(wm1, Wm1);
  prep_w<128, 128, 128><<<512, 256, 0, stream>>>(wm2, Wm2);
  prep_w<128, 576, 640><<<512, 256, 0, stream>>>(wm3, Wm3);
  prep_w<320, 128, 128><<<512, 256, 0, stream>>>(ww1, Ww1);
  prep_w<128, 576, 640><<<512, 256, 0, stream>>>(ww2, Ww2);

  upsample_cat_k<<<11520, 256, 0, stream>>>(z2, y1, cat);

  dim3 blk(256);
  dim3 gridA(48, 1, 8);   // COUTP=128
  dim3 gridC(48, 5, 8);   // COUTP=640

  // sigma branch
  conv5_k<320, 128, 128, 1, 0><<<gridA, blk, 0, stream>>>(cat, Ws1, bs1, nullptr, t1, nullptr);
  conv5_k<128, 128, 128, 1, 0><<<gridA, blk, 0, stream>>>(t1, Ws2, bs2, nullptr, t2, nullptr);
  conv5_k<128, 576, 640, 1, 1><<<gridC, blk, 0, stream>>>(t2, Ws3, bs3, out_sigma, nullptr, nullptr);
  // means branch
  conv5_k<320, 128, 128, 2, 0><<<gridA, blk, 0, stream>>>(cat, Wm1, bm1, nullptr, t1, nullptr);
  conv5_k<128, 128, 128, 2, 0><<<gridA, blk, 0, stream>>>(t1, Wm2, bm2, nullptr, t2, nullptr);
  conv5_k<128, 576, 640, 0, 1><<<gridC, blk, 0, stream>>>(t2, Wm3, bm3, out_means, nullptr, nullptr);
  // weights branch
  conv5_k<320, 128, 128, 2, 0><<<gridA, blk, 0, stream>>>(cat, Ww1, bw1, nullptr, t1, nullptr);
  conv5_k<128, 576, 640, 0, 2><<<gridC, blk, 0, stream>>>(t1, Ww2, bw2, nullptr, nullptr, part);
  reduce_max_k<<<18, 256, 0, stream>>>(part, pooled);
  tail_k<<<8, 256, 0, stream>>>(pooled, ww3, bw3, out_w);
}

// Round 2
// 3093.341 us; speedup vs baseline: 1.1089x; 1.1089x over previous
//
#include <hip/hip_runtime.h>

// ---------------------------------------------------------------------------
// gmm_hyper_y2 on MI355X: bf16 MFMA implicit-GEMM convs, NHWC bf16 acts,
// frag-order weights (global->reg), double-buffered global_load_lds staging,
// branch-fused dispatches.
// ---------------------------------------------------------------------------

typedef __attribute__((ext_vector_type(8))) short   short8;
typedef __attribute__((ext_vector_type(4))) float   f32x4;
typedef __attribute__((ext_vector_type(4))) unsigned short u16x4;

#define DEV __device__ __forceinline__
#define AS1 __attribute__((address_space(1)))
#define AS3 __attribute__((address_space(3)))

DEV unsigned short f2bf(float f) {           // RTNE f32 -> bf16
  union { float f; unsigned u; } v; v.f = f;
  unsigned u = v.u;
  u += 0x7fffu + ((u >> 16) & 1u);
  return (unsigned short)(u >> 16);
}

// ---------------- weight prep: OIHW f32 -> frag-order bf16 -----------------
// dst layout: [tap(25)][kt(CIN/32)][mt(COUTP/16)][lane(64)][j(8)]
template<int CIN, int COUT, int COUTP>
__global__ void prep_w(const float* __restrict__ w, unsigned short* __restrict__ dst) {
  const int KT = CIN / 32, MT = COUTP / 16;
  const int total = 25 * KT * MT * 512;
  for (int idx = blockIdx.x * blockDim.x + threadIdx.x; idx < total;
       idx += gridDim.x * blockDim.x) {
    int j   = idx & 7;
    int l   = (idx >> 3) & 63;
    int blk = idx >> 9;
    int mt  = blk % MT;
    int rst = blk / MT;
    int kt  = rst % KT;
    int tap = rst / KT;
    int ky = tap / 5, kx = tap % 5;
    int co = mt * 16 + (l & 15);
    int ci = kt * 32 + (l >> 4) * 8 + j;
    float val = (co < COUT) ? w[((co * CIN + ci) * 5 + ky) * 5 + kx] : 0.0f;
    dst[idx] = f2bf(val);
  }
}

// ------------- upsample z2 x4 bilinear + concat y1 -> NHWC bf16 ------------
__global__ void upsample_cat_k(const float* __restrict__ z2,
                               const float* __restrict__ y1,
                               unsigned short* __restrict__ cat) {
  int tid = blockIdx.x * blockDim.x + threadIdx.x;
  int p = tid % 9216;
  int rest = tid / 9216;
  int chunk = rest % 40;
  int b = rest / 40;
  if (b >= 8) return;
  int Y = p / 96, X = p % 96;
  short8 vec;
  if (chunk < 16) {
    const float s = 23.0f / 95.0f;
    float ys = Y * s, xs = X * s;
    float fy = floorf(ys), fx = floorf(xs);
    int y0 = (int)fy, x0 = (int)fx;
    int y1i = min(y0 + 1, 23), x1i = min(x0 + 1, 23);
    float wy = ys - fy, wx = xs - fx;
    int c0 = chunk * 8;
    const float* zb = z2 + ((size_t)b * 128 + c0) * 576;
#pragma unroll
    for (int i = 0; i < 8; ++i) {
      const float* zc = zb + (size_t)i * 576;
      float g00 = zc[y0 * 24 + x0],  g01 = zc[y0 * 24 + x1i];
      float g10 = zc[y1i * 24 + x0], g11 = zc[y1i * 24 + x1i];
      float top = g00 + (g01 - g00) * wx;
      float bot = g10 + (g11 - g10) * wx;
      vec[i] = (short)f2bf(top + (bot - top) * wy);
    }
  } else {
    int c0 = (chunk - 16) * 8;
    const float* yb = y1 + ((size_t)b * 192 + c0) * 9216 + p;
#pragma unroll
    for (int i = 0; i < 8; ++i) vec[i] = (short)f2bf(yb[(size_t)i * 9216]);
  }
  int cbase = (chunk < 16) ? chunk * 8 : 128 + (chunk - 16) * 8;
  *reinterpret_cast<short8*>(cat + ((size_t)(b * 9216 + p)) * 320 + cbase) = vec;
}

// --------------------------- 5x5 conv, pad 2 --------------------------------
// Block: 512 thr = 8 waves. wm = co-64-half, wn = row(2), wp = px-half(2).
// Wave tile: 4 co-frags x 3 px-frags (64 co x 48 px). Block: 128 co x 2r x 96px.
// LDS: 2 x 40 KiB double-buffered halo tile, staged via global_load_lds with
// pre-swizzled per-lane source (XOR chunk swizzle), zero-page for OOB.
struct BranchArgs {
  const unsigned short* in[3];
  const unsigned short* w[3];
  const float* bias[3];
  unsigned short* ob[3];
  float* of[3];
};

template<int CIN, int COUT, int COUTP, int ACT0, int ACT1, int ACT2, int OUTMODE>
__global__ __launch_bounds__(512, 4)
void conv5_k(BranchArgs args, const char* __restrict__ zp) {
  const int KT = CIN / 32, MT = COUTP / 16;
  __shared__ alignas(16) char lds[81920];      // 2 x (2560 chunks x 16 B)
  const int tid = threadIdx.x;
  const int l = tid & 63;
  const int wid = tid >> 6;
  const int wm = wid & 1, wn = (wid >> 1) & 1, wp = wid >> 2;
  const int rowtile = blockIdx.x;              // 0..47
  const int coblk = blockIdx.y * 128;
  const int bz = blockIdx.z;
  const int b = bz & 7, br = bz >> 3;
  const int y0 = rowtile * 2;
  const int lj = l >> 4, lx = l & 15;

  const unsigned short* act_in = args.in[br];
  const unsigned short* wfrag  = args.w[br];
  const int act = (br == 0) ? ACT0 : (br == 1 ? ACT1 : ACT2);

  // ---- per-thread staging descriptors (5 chunks of 16 B each) ----
  const char* sp[5];
  int ldst[5];
#pragma unroll
  for (int i = 0; i < 5; ++i) {
    int t = tid + i * 512;
    int p = t >> 2, q = t & 3;
    int r = p / 100, c = p - r * 100;
    int yy = y0 + r - 2, xx = c - 2;
    int ch = q ^ ((c >> 1) & 3);
    bool ok = (t < 2400) && ((unsigned)yy < 96u) && ((unsigned)xx < 96u);
    sp[i] = ok ? (const char*)(act_in + (size_t)((b * 96 + yy) * 96 + xx) * CIN + ch * 8)
               : zp;
    ldst[i] = t * 16;
  }

  f32x4 acc[4][3];
#pragma unroll
  for (int m = 0; m < 4; ++m)
#pragma unroll
    for (int n = 0; n < 3; ++n) acc[m][n] = f32x4{0.f, 0.f, 0.f, 0.f};

  auto stage = [&](int ktoff, int bufbase) {
#pragma unroll
    for (int i = 0; i < 5; ++i)
      __builtin_amdgcn_global_load_lds(
          (const AS1 unsigned int*)(sp[i] + ktoff),
          (AS3 unsigned int*)(lds + bufbase + ldst[i]), 16, 0, 0);
  };

  stage(0, 0);
  int cur = 0;
  const int mt0 = (coblk >> 4) + wm * 4;
  for (int kt = 0; kt < KT; ++kt) {
    __syncthreads();                           // drains vmcnt -> buf[cur] ready
    if (kt + 1 < KT) stage((kt + 1) * 64, (cur ^ 1) * 40960);
    const unsigned short* wb = wfrag + ((size_t)kt * MT + mt0) * 512 + l * 8;
    const char* lc = lds + cur * 40960;
    for (int ky = 0; ky < 5; ++ky) {
      const int r = wn + ky;
#pragma unroll
      for (int kx = 0; kx < 5; ++kx) {
        const int tap = ky * 5 + kx;
        short8 aW[4];
#pragma unroll
        for (int m = 0; m < 4; ++m)
          aW[m] = *reinterpret_cast<const short8*>(wb + ((size_t)tap * KT * MT + m) * 512);
        short8 bA[3];
#pragma unroll
        for (int n = 0; n < 3; ++n) {
          int c = kx + wp * 48 + n * 16 + lx;
          int off = ((r * 100 + c) << 6) + ((lj ^ ((c >> 1) & 3)) << 4);
          bA[n] = *reinterpret_cast<const short8*>(lc + off);
        }
#pragma unroll
        for (int m = 0; m < 4; ++m)
#pragma unroll
          for (int n = 0; n < 3; ++n)
            acc[m][n] = __builtin_amdgcn_mfma_f32_16x16x32_bf16(aW[m], bA[n], acc[m][n], 0, 0, 0);
      }
    }
    cur ^= 1;
  }

  const int yout = y0 + wn;
  if (OUTMODE == 0) {
    unsigned short* ob = args.ob[br];
#pragma unroll
    for (int m = 0; m < 4; ++m) {
      int co0 = coblk + wm * 64 + m * 16 + lj * 4;
      f32x4 bv = *reinterpret_cast<const f32x4*>(args.bias[br] + co0);
#pragma unroll
      for (int n = 0; n < 3; ++n) {
        int x = wp * 48 + n * 16 + lx;
        u16x4 pk;
#pragma unroll
        for (int j = 0; j < 4; ++j) {
          float v = acc[m][n][j] + bv[j];
          if (act == 1) v = fmaxf(v, 0.f);
          if (act == 2) v = (v >= 0.f) ? v : 0.01f * v;
          pk[j] = f2bf(v);
        }
        *reinterpret_cast<u16x4*>(ob + (size_t)((b * 96 + yout) * 96 + x) * COUT + co0) = pk;
      }
    }
  } else if (OUTMODE == 1) {
    float* of = args.of[br];
#pragma unroll
    for (int m = 0; m < 4; ++m) {
      int co0 = coblk + wm * 64 + m * 16 + lj * 4;
      if (co0 < COUT) {
        f32x4 bv = *reinterpret_cast<const f32x4*>(args.bias[br] + co0);
#pragma unroll
        for (int n = 0; n < 3; ++n) {
          int x = wp * 48 + n * 16 + lx;
#pragma unroll
          for (int j = 0; j < 4; ++j) {
            float v = acc[m][n][j] + bv[j];
            if (act == 1) v = fmaxf(v, 0.f);
            if (act == 2) v = (v >= 0.f) ? v : 0.01f * v;
            of[((size_t)(b * COUT + co0 + j) * 96 + yout) * 96 + x] = v;
          }
        }
      }
    }
  } else {  // OUTMODE == 2: conv+bias -> per-(row,px-half) max partials
    float* part = args.of[0];
#pragma unroll
    for (int m = 0; m < 4; ++m) {
      int co0 = coblk + wm * 64 + m * 16 + lj * 4;
      f32x4 bv = f32x4{0.f, 0.f, 0.f, 0.f};
      if (co0 < COUT) bv = *reinterpret_cast<const f32x4*>(args.bias[br] + co0);
#pragma unroll
      for (int j = 0; j < 4; ++j) {
        float mx = -3.0e38f;
#pragma unroll
        for (int n = 0; n < 3; ++n) mx = fmaxf(mx, acc[m][n][j] + bv[j]);
#pragma unroll
        for (int s = 1; s < 16; s <<= 1) mx = fmaxf(mx, __shfl_xor(mx, s, 64));
        if (lx == 0 && co0 + j < COUT)
          part[(size_t)(b * COUT + co0 + j) * 192 + (rowtile * 2 + wn) * 2 + wp] = mx;
      }
    }
  }
}

// --------------------- tail: reduce / 1x1 conv / softmax -------------------
__global__ void reduce_max_k(const float* __restrict__ part, float* __restrict__ pooled) {
  int i = blockIdx.x * blockDim.x + threadIdx.x;
  if (i >= 8 * 576) return;
  const float* p = part + (size_t)i * 192;
  float mx = p[0];
  for (int t = 1; t < 192; ++t) mx = fmaxf(mx, p[t]);
  pooled[i] = mx;
}

__global__ void tail_k(const float* __restrict__ pooled,
                       const float* __restrict__ ww3, const float* __restrict__ bw3,
                       float* __restrict__ outw) {
  __shared__ float g[576];
  __shared__ float h2[576];
  int b = blockIdx.x, tid = threadIdx.x;
  for (int i = tid; i < 576; i += 256) {
    float v = pooled[b * 576 + i];
    g[i] = (v >= 0.f) ? v : 0.01f * v;
  }
  __syncthreads();
  for (int o = tid; o < 576; o += 256) {
    float s = bw3[o];
    const float* wr = ww3 + (size_t)o * 576;
    for (int i = 0; i < 576; ++i) s += wr[i] * g[i];
    h2[o] = s;
  }
  __syncthreads();
  for (int m = tid; m < 192; m += 256) {
    float a0 = h2[m], a1 = h2[192 + m], a2 = h2[384 + m];
    float mx = fmaxf(a0, fmaxf(a1, a2));
    float e0 = expf(a0 - mx), e1 = expf(a1 - mx), e2 = expf(a2 - mx);
    float inv = 1.f / (e0 + e1 + e2);
    outw[b * 576 + m]       = e0 * inv;
    outw[b * 576 + 192 + m] = e1 * inv;
    outw[b * 576 + 384 + m] = e2 * inv;
  }
}

// ---------------------------------------------------------------------------
extern "C" void kernel_launch(void* const* d_in, const int* in_sizes, int n_in,
                              void* d_out, int out_size, void* d_ws, size_t ws_size,
                              hipStream_t stream) {
  const float* z2  = (const float*)d_in[0];
  const float* y1  = (const float*)d_in[1];
  const float* ws1 = (const float*)d_in[2];  const float* bs1 = (const float*)d_in[3];
  const float* ws2 = (const float*)d_in[4];  const float* bs2 = (const float*)d_in[5];
  const float* ws3 = (const float*)d_in[6];  const float* bs3 = (const float*)d_in[7];
  const float* wm1 = (const float*)d_in[8];  const float* bm1 = (const float*)d_in[9];
  const float* wm2 = (const float*)d_in[10]; const float* bm2 = (const float*)d_in[11];
  const float* wm3 = (const float*)d_in[12]; const float* bm3 = (const float*)d_in[13];
  const float* ww1 = (const float*)d_in[14]; const float* bw1 = (const float*)d_in[15];
  const float* ww2 = (const float*)d_in[16]; const float* bw2 = (const float*)d_in[17];
  const float* ww3 = (const float*)d_in[18]; const float* bw3 = (const float*)d_in[19];

  char* ws = (char*)d_ws;
  size_t off = 0;
  auto alloc = [&](size_t bytes) -> char* {
    char* p = ws + off;
    off += (bytes + 255) & ~(size_t)255;
    return p;
  };
  char* zp = alloc(4096);
  unsigned short* cat = (unsigned short*)alloc(8ull * 9216 * 320 * 2);
  unsigned short* t1s = (unsigned short*)alloc(8ull * 9216 * 128 * 2);
  unsigned short* t1m = (unsigned short*)alloc(8ull * 9216 * 128 * 2);
  unsigned short* t1w = (unsigned short*)alloc(8ull * 9216 * 128 * 2);
  const size_t szA = 25ull * 10 * 8 * 512;
  const size_t szB = 25ull * 4 * 8 * 512;
  const size_t szC = 25ull * 4 * 40 * 512;
  unsigned short* Ws1 = (unsigned short*)alloc(szA * 2);
  unsigned short* Ws2 = (unsigned short*)alloc(szB * 2);
  unsigned short* Ws3 = (unsigned short*)alloc(szC * 2);
  unsigned short* Wm1 = (unsigned short*)alloc(szA * 2);
  unsigned short* Wm2 = (unsigned short*)alloc(szB * 2);
  unsigned short* Wm3 = (unsigned short*)alloc(szC * 2);
  unsigned short* Ww1 = (unsigned short*)alloc(szA * 2);
  unsigned short* Ww2 = (unsigned short*)alloc(szC * 2);
  float* part   = (float*)alloc(8ull * 576 * 192 * 4);
  float* pooled = (float*)alloc(8ull * 576 * 4);
  // t2 buffers alias cat (fusedA finishes reading cat before fusedB writes t2)
  unsigned short* t2s = cat;
  unsigned short* t2m = cat + 8ull * 9216 * 128;

  float* out_sigma = (float*)d_out;
  float* out_means = out_sigma + 8ull * 576 * 9216;
  float* out_w     = out_means + 8ull * 576 * 9216;

  hipMemsetAsync(zp, 0, 4096, stream);

  prep_w<320, 128, 128><<<256, 256, 0, stream>>>(ws1, Ws1);
  prep_w<128, 128, 128><<<128, 256, 0, stream>>>(ws2, Ws2);
  prep_w<128, 576, 640><<<512, 256, 0, stream>>>(ws3, Ws3);
  prep_w<320, 128, 128><<<256, 256, 0, stream>>>(wm1, Wm1);
  prep_w<128, 128, 128><<<128, 256, 0, stream>>>(wm2, Wm2);
  prep_w<128, 576, 640><<<512, 256, 0, stream>>>(wm3, Wm3);
  prep_w<320, 128, 128><<<256, 256, 0, stream>>>(ww1, Ww1);
  prep_w<128, 576, 640><<<512, 256, 0, stream>>>(ww2, Ww2);

  upsample_cat_k<<<11520, 256, 0, stream>>>(z2, y1, cat);

  dim3 blk(512);

  // fused layer 1: sigma(relu) / means(lrelu) / weights(lrelu), cat -> t1*
  {
    BranchArgs a{};
    a.in[0] = cat; a.in[1] = cat; a.in[2] = cat;
    a.w[0] = Ws1; a.w[1] = Wm1; a.w[2] = Ww1;
    a.bias[0] = bs1; a.bias[1] = bm1; a.bias[2] = bw1;
    a.ob[0] = t1s; a.ob[1] = t1m; a.ob[2] = t1w;
    conv5_k<320, 128, 128, 1, 2, 2, 0><<<dim3(48, 1, 24), blk, 0, stream>>>(a, zp);
  }
  // fused layer 2: sigma(relu) / means(lrelu), t1* -> t2*
  {
    BranchArgs a{};
    a.in[0] = t1s; a.in[1] = t1m;
    a.w[0] = Ws2; a.w[1] = Wm2;
    a.bias[0] = bs2; a.bias[1] = bm2;
    a.ob[0] = t2s; a.ob[1] = t2m;
    conv5_k<128, 128, 128, 1, 2, 0, 0><<<dim3(48, 1, 16), blk, 0, stream>>>(a, zp);
  }
  // weights layer 2 conv + global-max partials (t1w -> part)
  {
    BranchArgs a{};
    a.in[0] = t1w;
    a.w[0] = Ww2;
    a.bias[0] = bw2;
    a.of[0] = part;
    conv5_k<128, 576, 640, 0, 0, 0, 2><<<dim3(48, 5, 8), blk, 0, stream>>>(a, zp);
  }
  // fused layer 3: sigma(relu, f32) / means(none, f32), t2* -> d_out
  {
    BranchArgs a{};
    a.in[0] = t2s; a.in[1] = t2m;
    a.w[0] = Ws3; a.w[1] = Wm3;
    a.bias[0] = bs3; a.bias[1] = bm3;
    a.of[0] = out_sigma; a.of[1] = out_means;
    conv5_k<128, 576, 640, 1, 0, 0, 1><<<dim3(48, 5, 16), blk, 0, stream>>>(a, zp);
  }

  reduce_max_k<<<18, 256, 0, stream>>>(part, pooled);
  tail_k<<<8, 256, 0, stream>>>(pooled, ww3, bw3, out_w);
}